// Round 5
// baseline (236.857 us; speedup 1.0000x reference)
//
#include <hip/hip_runtime.h>
#include <math.h>

// OrbitalCofactorAntiequivarianceLayer fused kernels for MI355X (gfx950).
// B=4096, NSPIN=2, NPS=16, D=256, NION=8, DIM=3.
//
// R10 -> R11: grid-level phase split. Four falsifications (memory residency,
// max waves, LDS traffic, shuffle volume, code size) pinned the wall on
// per-wave dependent-latency chains: each wave coupled a high-ILP streaming
// GEMM/env with a ~16-step serial shuffle-chain LU (~120cyc dependent
// ds_bpermute latency each), stretching wave lifetime to ~75-100K cycles.
// Split:
//   kernel 1 (cof_matrix, 2048x256): Phase A (direct-global GEMM) + bias +
//     envelope; writes M (8192 pairs x 256 floats = 8MB) to d_ws. Pure
//     streaming, no serial chains.
//   kernel 2 (cof_lu, 2048x64): LU cofactor, one wave = 4 DISTINCT pairs
//     (four 16-lane groups, R6-style dedup; gb logic unchanged).
// M values and LU op sequence identical -> bit-identical output.

// ---------------- kernel 1: M = (x@W + b) * env -> ws ----------------
__global__ __launch_bounds__(256)
void cof_matrix(const float* __restrict__ eq,    // (B,32,256)
                const float* __restrict__ rei,   // (B,32,8,3)
                const float* __restrict__ Wm,    // (2,256,16)
                const float* __restrict__ bb,    // (2,16)
                const float* __restrict__ edim,  // (2,8,16,3,3)
                const float* __restrict__ eion,  // (2,8,16)
                float* __restrict__ ws)          // (8192, 256) = M per pair
{
  __shared__ __align__(16) float Gl[8 * 6 * 16];   // Gram coeffs, SoA [i][c6][o]
  __shared__ __align__(16) float Xl[4 * 320];      // per-wave y (16 rows x stride 20)

  const int tid   = threadIdx.x;
  const int lane  = tid & 63;
  const int wv    = tid >> 6;
  const int blk   = blockIdx.x;
  const int sp    = blk >> 10;           // spin index
  const int bbase = (blk & 1023) * 4;

  // ---- Gram precompute: G = A^T A per (i,o), cross terms pre-doubled ----
  if (tid < 128) {
    const int i = tid >> 4, o = tid & 15;
    const float* A = edim + (((size_t)sp * 8 + i) * 16 + o) * 9;
    const float a0=A[0],a1=A[1],a2=A[2],a3=A[3],a4=A[4],a5=A[5],a6=A[6],a7=A[7],a8=A[8];
    float* Gp = Gl + i * 96 + o;
    Gp[0]  = a0*a0 + a3*a3 + a6*a6;
    Gp[16] = a1*a1 + a4*a4 + a7*a7;
    Gp[32] = a2*a2 + a5*a5 + a8*a8;
    Gp[48] = 2.f*(a0*a1 + a3*a4 + a6*a7);
    Gp[64] = 2.f*(a0*a2 + a3*a5 + a6*a8);
    Gp[80] = 2.f*(a1*a2 + a4*a5 + a7*a8);
  }
  __syncthreads();

  const int bidx = bbase + wv;
  const int cch  = lane >> 4;        // K-chunk within a 16-float group
  const int nb   = (lane >> 2) & 3;  // row-tile
  const int ob   = lane & 3;         // col-tile

  const float* xb = eq + ((size_t)bidx * 32 + sp * 16) * 256;
  const float* wb = Wm + (size_t)sp * 4096;

  float acc[4][4] = {{0.f,0.f,0.f,0.f},{0.f,0.f,0.f,0.f},
                     {0.f,0.f,0.f,0.f},{0.f,0.f,0.f,0.f}};

  // ---- Phase A: y = xs @ W, fragments loaded directly from global.
  // Lane (cch,nb,ob) accumulates rows 4nb..4nb+3 x cols 4ob..4ob+3 over
  // d = q*16 + cch*4 .. +3, q = 0..15; reduced over cch below.
  #pragma unroll
  for (int q = 0; q < 16; ++q) {
    const int dg = q * 16 + cch * 4;
    float xr[4][4], wr4[4][4];
    #pragma unroll
    for (int r = 0; r < 4; ++r) {
      float4 t = *(const float4*)(xb + (4 * nb + r) * 256 + dg);
      xr[r][0]=t.x; xr[r][1]=t.y; xr[r][2]=t.z; xr[r][3]=t.w;
    }
    #pragma unroll
    for (int j = 0; j < 4; ++j) {
      float4 t = *(const float4*)(wb + (dg + j) * 16 + 4 * ob);
      wr4[j][0]=t.x; wr4[j][1]=t.y; wr4[j][2]=t.z; wr4[j][3]=t.w;
    }
    #pragma unroll
    for (int r = 0; r < 4; ++r)
      #pragma unroll
      for (int j = 0; j < 4; ++j)
        #pragma unroll
        for (int c2 = 0; c2 < 4; ++c2)
          acc[r][c2] = fmaf(xr[r][j], wr4[j][c2], acc[r][c2]);
  }

  // reduce over K-chunks (lane bits 4-5)
  #pragma unroll
  for (int r = 0; r < 4; ++r)
    #pragma unroll
    for (int c2 = 0; c2 < 4; ++c2) {
      float v = acc[r][c2];
      v += __shfl_xor(v, 16);
      v += __shfl_xor(v, 32);
      acc[r][c2] = v;
    }

  // y (pre-env) in this wave's LDS slice, 16 rows, stride 20 floats.
  float* Mw = Xl + wv * 320;
  {
    float4 bv = *(const float4*)(bb + sp * 16 + 4 * ob);
    if (lane < 16) {
      #pragma unroll
      for (int r = 0; r < 4; ++r) {
        float4 v = make_float4(acc[r][0] + bv.x, acc[r][1] + bv.y,
                               acc[r][2] + bv.z, acc[r][3] + bv.w);
        *(float4*)(Mw + (4 * nb + r) * 20 + 4 * ob) = v;
      }
    }
  }

  // ---- Phase C: envelope; M = y * env -> ws (coalesced float4 store) ----
  {
    const int n = lane >> 2;           // row 0..15, cols 4*ob..4*ob+3
    const float* rp = rei + ((size_t)bidx * 32 + sp * 16 + n) * 24;
    float rv[24];
    #pragma unroll
    for (int t4 = 0; t4 < 6; ++t4) {
      float4 t = *(const float4*)(rp + t4 * 4);
      rv[t4*4+0]=t.x; rv[t4*4+1]=t.y; rv[t4*4+2]=t.z; rv[t4*4+3]=t.w;
    }
    float4 env = make_float4(0.f, 0.f, 0.f, 0.f);
    #pragma unroll
    for (int i = 0; i < 8; ++i) {
      const float r0 = rv[i*3], r1 = rv[i*3+1], r2 = rv[i*3+2];
      const float rr0 = r0*r0, rr1 = r1*r1, rr2 = r2*r2;
      const float rr3 = r0*r1, rr4 = r0*r2, rr5 = r1*r2;
      const float* Gp = Gl + i * 96 + 4 * ob;
      const float4 q00 = *(const float4*)(Gp);
      const float4 q11 = *(const float4*)(Gp + 16);
      const float4 q22 = *(const float4*)(Gp + 32);
      const float4 q01 = *(const float4*)(Gp + 48);
      const float4 q02 = *(const float4*)(Gp + 64);
      const float4 q12 = *(const float4*)(Gp + 80);
      const float4 io  = *(const float4*)(eion + ((size_t)sp * 8 + i) * 16 + 4 * ob);
#define ENVC(c) { float n2 = q00.c*rr0 + q11.c*rr1 + q22.c*rr2 \
                           + q01.c*rr3 + q02.c*rr4 + q12.c*rr5; \
                  n2 = fmaxf(n2, 0.f); \
                  env.c += __expf(-sqrtf(n2)) * io.c; }
      ENVC(x) ENVC(y) ENVC(z) ENVC(w)
#undef ENVC
    }
    const float* mp = Mw + n * 20 + 4 * ob;
    float4 y = *(const float4*)mp;
    const size_t pair = (size_t)bidx * 2 + sp;
    // lanes 0..63 -> offsets 0,4,...,252: fully coalesced 1KB/wave store
    *(float4*)(ws + pair * 256 + n * 16 + 4 * ob) =
        make_float4(y.x * env.x, y.y * env.y, y.z * env.z, y.w * env.w);
  }
}

// ---------------- kernel 2: cofactor via 16-lane LU ----------------
// One wave per block (64 threads); four 16-lane groups handle FOUR distinct
// pairs. A = M^T, fp32 LU with virtual partial pivoting;
// cof[i] = M[i,0]*det*x[i], x = A^{-1} e0 (= row 0 of M^{-1}).
__global__ __launch_bounds__(64)
void cof_lu(const float* __restrict__ ws,   // (8192, 256)
            float* __restrict__ out)        // (B,2,16) = (8192,16)
{
  const int lane = threadIdx.x;
  const int g  = lane >> 4;        // group -> pair within block
  const int r  = lane & 15;        // my row of A (= column r of M)
  const int gb = lane & 48;        // group base for shuffles
  const size_t pair = (size_t)blockIdx.x * 4 + g;
  const float* mg = ws + pair * 256;

  float a[16];
  #pragma unroll
  for (int c = 0; c < 16; ++c) a[c] = mg[c * 16 + r];

  float det = 1.0f;
  int sign = 0;
  unsigned retired = 0;
  unsigned pp0 = 0, pp1 = 0;       // packed pivot indices, 4 bits each
  int srr = 0;
  float accf = (r == 0) ? 1.0f : 0.0f;  // forward rhs (P e0 component)
  float acc2 = 0.0f;                    // z captured at my retirement

  #pragma unroll
  for (int k = 0; k < 16; ++k) {
    const bool act = ((retired >> r) & 1u) == 0u;
    const float av = act ? fabsf(a[k]) : 0.0f;
    unsigned pk = (__float_as_uint(av) & 0xFFFFFFF0u) | (unsigned)r;
    #pragma unroll
    for (int m = 1; m <= 8; m <<= 1) {
      unsigned o2 = __shfl_xor(pk, m);
      pk = (pk > o2) ? pk : o2;
    }
    const int p = (int)(pk & 15u);
    if (k < 8) pp0 |= (unsigned)p << (4 * k);
    else       pp1 |= (unsigned)p << (4 * (k - 8));
    float pv = __shfl(a[k], gb | p);
    if (fabsf(pv) < 1e-30f) pv = (pv < 0.0f) ? -1e-30f : 1e-30f;
    det *= pv;
    retired |= (1u << p);
    sign ^= (int)(__popc((~retired) & ((1u << p) - 1u)) & 1u);
    if (r == p) srr = k;
    const bool upd = act && (r != p);
    float m2 = 0.0f;
    if (upd) { m2 = a[k] / pv; a[k] = m2; }
    #pragma unroll
    for (int c = k + 1; c < 16; ++c) {
      float bcv = __shfl(a[c], gb | p);
      if (upd) a[c] = fmaf(-m2, bcv, a[c]);
    }
    // fused forward solve L z = P e0
    float zk = __shfl(accf, gb | p);
    if (r == p) acc2 = zk;
    if (upd) accf = fmaf(-m2, zk, accf);
  }
  if (sign) det = -det;

  // backward solve U x = z
  float myx = 0.0f;
  #pragma unroll
  for (int j = 15; j >= 0; --j) {
    float t = acc2 / a[j];                   // valid on pivot lane of step j
    const int pj = (int)(((j >= 8) ? (pp1 >> (4 * (j - 8)))
                                   : (pp0 >> (4 * j))) & 15u);
    float xj = __shfl(t, gb | pj);
    if (srr < j) acc2 = fmaf(-a[j], xj, acc2);
    if (r == j) myx = xj;
  }

  const float mi0 = mg[r * 16];              // M[r][0]
  out[pair * 16 + r] = mi0 * det * myx;      // all 64 lanes: 4 pairs x 16
}

extern "C" void kernel_launch(void* const* d_in, const int* in_sizes, int n_in,
                              void* d_out, int out_size, void* d_ws, size_t ws_size,
                              hipStream_t stream) {
  (void)in_sizes; (void)n_in; (void)out_size; (void)ws_size;
  const float* eq   = (const float*)d_in[0];
  const float* rei  = (const float*)d_in[1];
  const float* Wm   = (const float*)d_in[2];
  const float* bb   = (const float*)d_in[3];
  const float* edim = (const float*)d_in[4];
  const float* eion = (const float*)d_in[5];
  float* out = (float*)d_out;
  float* ws  = (float*)d_ws;   // needs 8192*256*4 = 8 MB
  hipLaunchKernelGGL(cof_matrix, dim3(2048), dim3(256), 0, stream,
                     eq, rei, Wm, bb, edim, eion, ws);
  hipLaunchKernelGGL(cof_lu, dim3(2048), dim3(64), 0, stream, ws, out);
}

// Round 6
// 232.735 us; speedup vs baseline: 1.0177x; 1.0177x over previous
//
#include <hip/hip_runtime.h>
#include <math.h>

// OrbitalCofactorAntiequivarianceLayer kernels for MI355X (gfx950).
// B=4096, NSPIN=2, NPS=16, D=256, NION=8, DIM=3.
//
// R11 -> R12: R11's split showed cof_lu ~7us and cof_matrix ~80us, with
// cof_matrix ALSO invariant to memory residency (cached re-run 81us) and
// VALU only 29% busy. Diagnosis: per-wave in-order waitcnt convoys -- each
// wave has ~1 q-iteration of load lookahead (compiler stopped at 64 VGPR),
// lives ~69K cycles while issuing ~7K. Fix: TWO pairs (same spin) per wave.
// Every load/FMA has an independent twin to fill stall slots; W-fragment
// loads and Gram/eion reads are shared between twins. Per-pair FP order
// unchanged -> bit-identical. Grid 1024x256; cof_lu unchanged (2048x64).

// ---------------- kernel 1: M = (x@W + b) * env -> ws ----------------
__global__ __launch_bounds__(256)
void cof_matrix(const float* __restrict__ eq,    // (B,32,256)
                const float* __restrict__ rei,   // (B,32,8,3)
                const float* __restrict__ Wm,    // (2,256,16)
                const float* __restrict__ bb,    // (2,16)
                const float* __restrict__ edim,  // (2,8,16,3,3)
                const float* __restrict__ eion,  // (2,8,16)
                float* __restrict__ ws)          // (8192, 256) = M per pair
{
  __shared__ __align__(16) float Gl[8 * 6 * 16];   // Gram coeffs, SoA [i][c6][o]
  __shared__ __align__(16) float Xl[8 * 320];      // per-pair y (16 rows x stride 20)

  const int tid   = threadIdx.x;
  const int lane  = tid & 63;
  const int wv    = tid >> 6;
  const int blk   = blockIdx.x;
  const int sp    = blk >> 9;            // 1024 blocks: 512 per spin
  const int bbase = (blk & 511) * 8;

  // ---- Gram precompute: G = A^T A per (i,o), cross terms pre-doubled ----
  if (tid < 128) {
    const int i = tid >> 4, o = tid & 15;
    const float* A = edim + (((size_t)sp * 8 + i) * 16 + o) * 9;
    const float a0=A[0],a1=A[1],a2=A[2],a3=A[3],a4=A[4],a5=A[5],a6=A[6],a7=A[7],a8=A[8];
    float* Gp = Gl + i * 96 + o;
    Gp[0]  = a0*a0 + a3*a3 + a6*a6;
    Gp[16] = a1*a1 + a4*a4 + a7*a7;
    Gp[32] = a2*a2 + a5*a5 + a8*a8;
    Gp[48] = 2.f*(a0*a1 + a3*a4 + a6*a7);
    Gp[64] = 2.f*(a0*a2 + a3*a5 + a6*a8);
    Gp[80] = 2.f*(a1*a2 + a4*a5 + a7*a8);
  }
  __syncthreads();

  const int bidx0 = bbase + wv * 2;      // two consecutive b per wave
  const int bidx1 = bidx0 + 1;
  const int cch  = lane >> 4;        // K-chunk within a 16-float group
  const int nb   = (lane >> 2) & 3;  // row-tile
  const int ob   = lane & 3;         // col-tile

  const float* xb0 = eq + ((size_t)bidx0 * 32 + sp * 16) * 256;
  const float* xb1 = eq + ((size_t)bidx1 * 32 + sp * 16) * 256;
  const float* wb  = Wm + (size_t)sp * 4096;

  float acc0[4][4] = {{0.f,0.f,0.f,0.f},{0.f,0.f,0.f,0.f},
                      {0.f,0.f,0.f,0.f},{0.f,0.f,0.f,0.f}};
  float acc1[4][4] = {{0.f,0.f,0.f,0.f},{0.f,0.f,0.f,0.f},
                      {0.f,0.f,0.f,0.f},{0.f,0.f,0.f,0.f}};

  // ---- Phase A: y = xs @ W for BOTH pairs. Lane (cch,nb,ob) accumulates
  // rows 4nb..4nb+3 x cols 4ob..4ob+3 over d = q*16+cch*4..+3, q=0..15.
  // W fragments shared between the twins; per-pair FMA order identical to
  // the single-pair version -> bit-identical results.
  #pragma unroll
  for (int q = 0; q < 16; ++q) {
    const int dg = q * 16 + cch * 4;
    float xr0[4][4], xr1[4][4], wr4[4][4];
    #pragma unroll
    for (int r = 0; r < 4; ++r) {
      float4 t = *(const float4*)(xb0 + (4 * nb + r) * 256 + dg);
      xr0[r][0]=t.x; xr0[r][1]=t.y; xr0[r][2]=t.z; xr0[r][3]=t.w;
    }
    #pragma unroll
    for (int r = 0; r < 4; ++r) {
      float4 t = *(const float4*)(xb1 + (4 * nb + r) * 256 + dg);
      xr1[r][0]=t.x; xr1[r][1]=t.y; xr1[r][2]=t.z; xr1[r][3]=t.w;
    }
    #pragma unroll
    for (int j = 0; j < 4; ++j) {
      float4 t = *(const float4*)(wb + (dg + j) * 16 + 4 * ob);
      wr4[j][0]=t.x; wr4[j][1]=t.y; wr4[j][2]=t.z; wr4[j][3]=t.w;
    }
    #pragma unroll
    for (int r = 0; r < 4; ++r)
      #pragma unroll
      for (int j = 0; j < 4; ++j)
        #pragma unroll
        for (int c2 = 0; c2 < 4; ++c2) {
          acc0[r][c2] = fmaf(xr0[r][j], wr4[j][c2], acc0[r][c2]);
          acc1[r][c2] = fmaf(xr1[r][j], wr4[j][c2], acc1[r][c2]);
        }
  }

  // reduce over K-chunks (lane bits 4-5), both pairs
  #pragma unroll
  for (int r = 0; r < 4; ++r)
    #pragma unroll
    for (int c2 = 0; c2 < 4; ++c2) {
      float v0 = acc0[r][c2], v1 = acc1[r][c2];
      v0 += __shfl_xor(v0, 16);
      v1 += __shfl_xor(v1, 16);
      v0 += __shfl_xor(v0, 32);
      v1 += __shfl_xor(v1, 32);
      acc0[r][c2] = v0;
      acc1[r][c2] = v1;
    }

  // y (pre-env) in this wave's two LDS slices, 16 rows, stride 20 floats.
  float* Mw0 = Xl + (wv * 2    ) * 320;
  float* Mw1 = Xl + (wv * 2 + 1) * 320;
  {
    float4 bv = *(const float4*)(bb + sp * 16 + 4 * ob);
    if (lane < 16) {
      #pragma unroll
      for (int r = 0; r < 4; ++r) {
        float4 v0 = make_float4(acc0[r][0] + bv.x, acc0[r][1] + bv.y,
                                acc0[r][2] + bv.z, acc0[r][3] + bv.w);
        float4 v1 = make_float4(acc1[r][0] + bv.x, acc1[r][1] + bv.y,
                                acc1[r][2] + bv.z, acc1[r][3] + bv.w);
        *(float4*)(Mw0 + (4 * nb + r) * 20 + 4 * ob) = v0;
        *(float4*)(Mw1 + (4 * nb + r) * 20 + 4 * ob) = v1;
      }
    }
  }

  // ---- Phase C: envelope for BOTH pairs; M = y * env -> ws ----
  {
    const int n = lane >> 2;           // row 0..15, cols 4*ob..4*ob+3
    const float* rp0 = rei + ((size_t)bidx0 * 32 + sp * 16 + n) * 24;
    const float* rp1 = rei + ((size_t)bidx1 * 32 + sp * 16 + n) * 24;
    float rv0[24], rv1[24];
    #pragma unroll
    for (int t4 = 0; t4 < 6; ++t4) {
      float4 t = *(const float4*)(rp0 + t4 * 4);
      rv0[t4*4+0]=t.x; rv0[t4*4+1]=t.y; rv0[t4*4+2]=t.z; rv0[t4*4+3]=t.w;
      float4 u = *(const float4*)(rp1 + t4 * 4);
      rv1[t4*4+0]=u.x; rv1[t4*4+1]=u.y; rv1[t4*4+2]=u.z; rv1[t4*4+3]=u.w;
    }
    float4 env0 = make_float4(0.f, 0.f, 0.f, 0.f);
    float4 env1 = make_float4(0.f, 0.f, 0.f, 0.f);
    #pragma unroll
    for (int i = 0; i < 8; ++i) {
      const float s0 = rv0[i*3], s1 = rv0[i*3+1], s2 = rv0[i*3+2];
      const float u0 = rv1[i*3], u1 = rv1[i*3+1], u2 = rv1[i*3+2];
      const float p0 = s0*s0, p1 = s1*s1, p2 = s2*s2;
      const float p3 = s0*s1, p4 = s0*s2, p5 = s1*s2;
      const float w0 = u0*u0, w1 = u1*u1, w2 = u2*u2;
      const float w3 = u0*u1, w4 = u0*u2, w5 = u1*u2;
      const float* Gp = Gl + i * 96 + 4 * ob;
      const float4 q00 = *(const float4*)(Gp);
      const float4 q11 = *(const float4*)(Gp + 16);
      const float4 q22 = *(const float4*)(Gp + 32);
      const float4 q01 = *(const float4*)(Gp + 48);
      const float4 q02 = *(const float4*)(Gp + 64);
      const float4 q12 = *(const float4*)(Gp + 80);
      const float4 io  = *(const float4*)(eion + ((size_t)sp * 8 + i) * 16 + 4 * ob);
#define ENVC(c) { float n2a = q00.c*p0 + q11.c*p1 + q22.c*p2 \
                            + q01.c*p3 + q02.c*p4 + q12.c*p5; \
                  float n2b = q00.c*w0 + q11.c*w1 + q22.c*w2 \
                            + q01.c*w3 + q02.c*w4 + q12.c*w5; \
                  n2a = fmaxf(n2a, 0.f); \
                  n2b = fmaxf(n2b, 0.f); \
                  env0.c += __expf(-sqrtf(n2a)) * io.c; \
                  env1.c += __expf(-sqrtf(n2b)) * io.c; }
      ENVC(x) ENVC(y) ENVC(z) ENVC(w)
#undef ENVC
    }
    const float* mp0 = Mw0 + n * 20 + 4 * ob;
    const float* mp1 = Mw1 + n * 20 + 4 * ob;
    float4 y0 = *(const float4*)mp0;
    float4 y1 = *(const float4*)mp1;
    const size_t pr0 = (size_t)bidx0 * 2 + sp;
    const size_t pr1 = (size_t)bidx1 * 2 + sp;
    // lanes 0..63 -> offsets 0,4,...,252: fully coalesced 1KB/wave stores
    *(float4*)(ws + pr0 * 256 + n * 16 + 4 * ob) =
        make_float4(y0.x * env0.x, y0.y * env0.y, y0.z * env0.z, y0.w * env0.w);
    *(float4*)(ws + pr1 * 256 + n * 16 + 4 * ob) =
        make_float4(y1.x * env1.x, y1.y * env1.y, y1.z * env1.z, y1.w * env1.w);
  }
}

// ---------------- kernel 2: cofactor via 16-lane LU ----------------
// One wave per block (64 threads); four 16-lane groups handle FOUR distinct
// pairs. A = M^T, fp32 LU with virtual partial pivoting;
// cof[i] = M[i,0]*det*x[i], x = A^{-1} e0 (= row 0 of M^{-1}).
__global__ __launch_bounds__(64)
void cof_lu(const float* __restrict__ ws,   // (8192, 256)
            float* __restrict__ out)        // (B,2,16) = (8192,16)
{
  const int lane = threadIdx.x;
  const int g  = lane >> 4;        // group -> pair within block
  const int r  = lane & 15;        // my row of A (= column r of M)
  const int gb = lane & 48;        // group base for shuffles
  const size_t pair = (size_t)blockIdx.x * 4 + g;
  const float* mg = ws + pair * 256;

  float a[16];
  #pragma unroll
  for (int c = 0; c < 16; ++c) a[c] = mg[c * 16 + r];

  float det = 1.0f;
  int sign = 0;
  unsigned retired = 0;
  unsigned pp0 = 0, pp1 = 0;       // packed pivot indices, 4 bits each
  int srr = 0;
  float accf = (r == 0) ? 1.0f : 0.0f;  // forward rhs (P e0 component)
  float acc2 = 0.0f;                    // z captured at my retirement

  #pragma unroll
  for (int k = 0; k < 16; ++k) {
    const bool act = ((retired >> r) & 1u) == 0u;
    const float av = act ? fabsf(a[k]) : 0.0f;
    unsigned pk = (__float_as_uint(av) & 0xFFFFFFF0u) | (unsigned)r;
    #pragma unroll
    for (int m = 1; m <= 8; m <<= 1) {
      unsigned o2 = __shfl_xor(pk, m);
      pk = (pk > o2) ? pk : o2;
    }
    const int p = (int)(pk & 15u);
    if (k < 8) pp0 |= (unsigned)p << (4 * k);
    else       pp1 |= (unsigned)p << (4 * (k - 8));
    float pv = __shfl(a[k], gb | p);
    if (fabsf(pv) < 1e-30f) pv = (pv < 0.0f) ? -1e-30f : 1e-30f;
    det *= pv;
    retired |= (1u << p);
    sign ^= (int)(__popc((~retired) & ((1u << p) - 1u)) & 1u);
    if (r == p) srr = k;
    const bool upd = act && (r != p);
    float m2 = 0.0f;
    if (upd) { m2 = a[k] / pv; a[k] = m2; }
    #pragma unroll
    for (int c = k + 1; c < 16; ++c) {
      float bcv = __shfl(a[c], gb | p);
      if (upd) a[c] = fmaf(-m2, bcv, a[c]);
    }
    // fused forward solve L z = P e0
    float zk = __shfl(accf, gb | p);
    if (r == p) acc2 = zk;
    if (upd) accf = fmaf(-m2, zk, accf);
  }
  if (sign) det = -det;

  // backward solve U x = z
  float myx = 0.0f;
  #pragma unroll
  for (int j = 15; j >= 0; --j) {
    float t = acc2 / a[j];                   // valid on pivot lane of step j
    const int pj = (int)(((j >= 8) ? (pp1 >> (4 * (j - 8)))
                                   : (pp0 >> (4 * j))) & 15u);
    float xj = __shfl(t, gb | pj);
    if (srr < j) acc2 = fmaf(-a[j], xj, acc2);
    if (r == j) myx = xj;
  }

  const float mi0 = mg[r * 16];              // M[r][0]
  out[pair * 16 + r] = mi0 * det * myx;      // all 64 lanes: 4 pairs x 16
}

extern "C" void kernel_launch(void* const* d_in, const int* in_sizes, int n_in,
                              void* d_out, int out_size, void* d_ws, size_t ws_size,
                              hipStream_t stream) {
  (void)in_sizes; (void)n_in; (void)out_size; (void)ws_size;
  const float* eq   = (const float*)d_in[0];
  const float* rei  = (const float*)d_in[1];
  const float* Wm   = (const float*)d_in[2];
  const float* bb   = (const float*)d_in[3];
  const float* edim = (const float*)d_in[4];
  const float* eion = (const float*)d_in[5];
  float* out = (float*)d_out;
  float* ws  = (float*)d_ws;   // needs 8192*256*4 = 8 MB
  hipLaunchKernelGGL(cof_matrix, dim3(1024), dim3(256), 0, stream,
                     eq, rei, Wm, bb, edim, eion, ws);
  hipLaunchKernelGGL(cof_lu, dim3(2048), dim3(64), 0, stream, ws, out);
}

// Round 7
// 224.595 us; speedup vs baseline: 1.0546x; 1.0362x over previous
//
#include <hip/hip_runtime.h>
#include <math.h>

// OrbitalCofactorAntiequivarianceLayer kernels for MI355X (gfx950).
// B=4096, NSPIN=2, NPS=16, D=256, NION=8, DIM=3.
//
// R12 -> R13: bench decomposition: ~155us of the 232us is harness poison-
// fills (2x 512MB @ 6.9TB/s); controllable part = cof_matrix ~70us + cof_lu
// ~7us. New mechanism for the stuck 70us: vmcnt retires IN ISSUE ORDER, so
// the per-g W global loads' waits drained the x-prefetch every sub-iteration
// in ALL previous versions -- the pipelines never pipelined.
// Fix: W staged to LDS once per block (16KB); the q-loop's only VMEM is the
// x prefetch (4 coalesced 1KB loads/quarter, unique bytes; VMEM instrs/pair
// 192 -> 16), reg->LDS issue-early/write-late, per-wave-private double
// buffer (no barriers; same-wave DS ordering), full-row XOR swizzle.
// FMA order/values unchanged -> bit-identical. cof_lu unchanged (~7us).

// ---------------- kernel 1: M = (x@W + b) * env -> ws ----------------
__global__ __launch_bounds__(256)
void cof_matrix(const float* __restrict__ eq,    // (B,32,256)
                const float* __restrict__ rei,   // (B,32,8,3)
                const float* __restrict__ Wm,    // (2,256,16)
                const float* __restrict__ bb,    // (2,16)
                const float* __restrict__ edim,  // (2,8,16,3,3)
                const float* __restrict__ eion,  // (2,8,16)
                float* __restrict__ ws)          // (8192, 256) = M per pair
{
  __shared__ __align__(16) float Wp[4096];        // W[sp] packed [256][16], 16 KB
  __shared__ __align__(16) float Gl[8 * 6 * 16];  // Gram coeffs, SoA [i][c6][o]
  __shared__ __align__(16) float Xs[4][2][1024];  // per-wave x quarter dbuf, 32 KB

  const int tid   = threadIdx.x;
  const int lane  = tid & 63;
  const int wv    = tid >> 6;
  const int blk   = blockIdx.x;
  const int sp    = blk >> 10;           // spin index
  const int bbase = (blk & 1023) * 4;

  const float* wb = Wm + (size_t)sp * 4096;

  // ---- W -> LDS (coalesced, once per block) ----
  #pragma unroll
  for (int t = 0; t < 4; ++t) {
    const int idx = t * 256 + tid;       // float4 index, 1024 total
    ((float4*)Wp)[idx] = ((const float4*)wb)[idx];
  }

  // ---- Gram precompute: G = A^T A per (i,o), cross terms pre-doubled ----
  if (tid < 128) {
    const int i = tid >> 4, o = tid & 15;
    const float* A = edim + (((size_t)sp * 8 + i) * 16 + o) * 9;
    const float a0=A[0],a1=A[1],a2=A[2],a3=A[3],a4=A[4],a5=A[5],a6=A[6],a7=A[7],a8=A[8];
    float* Gp = Gl + i * 96 + o;
    Gp[0]  = a0*a0 + a3*a3 + a6*a6;
    Gp[16] = a1*a1 + a4*a4 + a7*a7;
    Gp[32] = a2*a2 + a5*a5 + a8*a8;
    Gp[48] = 2.f*(a0*a1 + a3*a4 + a6*a7);
    Gp[64] = 2.f*(a0*a2 + a3*a5 + a6*a8);
    Gp[80] = 2.f*(a1*a2 + a4*a5 + a7*a8);
  }
  __syncthreads();

  const int bidx = bbase + wv;
  const int cch  = lane >> 4;        // K-chunk within a 16-float group
  const int nb   = (lane >> 2) & 3;  // row-tile
  const int ob   = lane & 3;         // col-tile

  const float* xb = eq + ((size_t)bidx * 32 + sp * 16) * 256;

  const int srow = lane >> 4;        // staging row base 0..3
  const int schk = lane & 15;        // staging float4-chunk within 64-float row

  float* xw0 = &Xs[wv][0][0];
  float* xw1 = &Xs[wv][1][0];

  float acc[4][4] = {{0.f,0.f,0.f,0.f},{0.f,0.f,0.f,0.f},
                     {0.f,0.f,0.f,0.f},{0.f,0.f,0.f,0.f}};

  // ---- Phase A: y = xs @ W. x staged in 16x64 quarters via reg->LDS with
  // issue-early / write-late; W fragments read from LDS (NO VMEM in the
  // compute path -> x prefetch vmcnt never force-drained). Full-row XOR
  // swizzle: LDS slot u of row R holds global chunk u^R (involution).
  float4 sA[4], sB[4];

#define LOADQ(dst, qq)                                                        \
  _Pragma("unroll")                                                           \
  for (int t = 0; t < 4; ++t)                                                 \
    dst[t] = *(const float4*)(xb + (4 * t + srow) * 256 + (qq) * 64 + schk * 4);

#define WRITEQ(buf, src)                                                      \
  _Pragma("unroll")                                                           \
  for (int t = 0; t < 4; ++t) {                                               \
    const int row_ = 4 * t + srow;                                            \
    *(float4*)((buf) + row_ * 64 + ((schk ^ row_) << 2)) = src[t];            \
  }

#define COMPQ(buf, qq)                                                        \
  _Pragma("unroll")                                                           \
  for (int g = 0; g < 4; ++g) {                                               \
    const int dg = (qq) * 64 + g * 16 + cch * 4;                              \
    float xr[4][4], wr4[4][4];                                                \
    _Pragma("unroll")                                                         \
    for (int r = 0; r < 4; ++r) {                                             \
      const int R_ = 4 * nb + r;                                              \
      float4 t = *(const float4*)((buf) + R_ * 64 +                           \
                                  (((g * 4 + cch) ^ R_) << 2));               \
      xr[r][0]=t.x; xr[r][1]=t.y; xr[r][2]=t.z; xr[r][3]=t.w;                 \
    }                                                                         \
    _Pragma("unroll")                                                         \
    for (int j = 0; j < 4; ++j) {                                             \
      float4 t = *(const float4*)(Wp + (dg + j) * 16 + 4 * ob);               \
      wr4[j][0]=t.x; wr4[j][1]=t.y; wr4[j][2]=t.z; wr4[j][3]=t.w;             \
    }                                                                         \
    _Pragma("unroll")                                                         \
    for (int r = 0; r < 4; ++r)                                               \
      _Pragma("unroll")                                                       \
      for (int j = 0; j < 4; ++j)                                             \
        _Pragma("unroll")                                                     \
        for (int c2 = 0; c2 < 4; ++c2)                                        \
          acc[r][c2] = fmaf(xr[r][j], wr4[j][c2], acc[r][c2]);                \
  }

  LOADQ(sA, 0)
  WRITEQ(xw0, sA)
  LOADQ(sB, 1)
  COMPQ(xw0, 0)        // Q1 latency hides under this
  WRITEQ(xw1, sB)
  LOADQ(sA, 2)
  COMPQ(xw1, 1)        // Q2 latency hides under this
  WRITEQ(xw0, sA)
  LOADQ(sB, 3)
  COMPQ(xw0, 2)        // Q3 latency hides under this
  WRITEQ(xw1, sB)
  COMPQ(xw1, 3)

#undef LOADQ
#undef WRITEQ
#undef COMPQ

  // reduce over K-chunks (lane bits 4-5)
  #pragma unroll
  for (int r = 0; r < 4; ++r)
    #pragma unroll
    for (int c2 = 0; c2 < 4; ++c2) {
      float v = acc[r][c2];
      v += __shfl_xor(v, 16);
      v += __shfl_xor(v, 32);
      acc[r][c2] = v;
    }

  // y (pre-env) overlays this wave's xw0 buffer (x fully consumed):
  // 16 rows, stride 20 floats.
  float* Mw = xw0;
  {
    float4 bv = *(const float4*)(bb + sp * 16 + 4 * ob);
    if (lane < 16) {
      #pragma unroll
      for (int r = 0; r < 4; ++r) {
        float4 v = make_float4(acc[r][0] + bv.x, acc[r][1] + bv.y,
                               acc[r][2] + bv.z, acc[r][3] + bv.w);
        *(float4*)(Mw + (4 * nb + r) * 20 + 4 * ob) = v;
      }
    }
  }

  // ---- Phase C: envelope; M = y * env -> ws (coalesced float4 store) ----
  {
    const int n = lane >> 2;           // row 0..15, cols 4*ob..4*ob+3
    const float* rp = rei + ((size_t)bidx * 32 + sp * 16 + n) * 24;
    float rv[24];
    #pragma unroll
    for (int t4 = 0; t4 < 6; ++t4) {
      float4 t = *(const float4*)(rp + t4 * 4);
      rv[t4*4+0]=t.x; rv[t4*4+1]=t.y; rv[t4*4+2]=t.z; rv[t4*4+3]=t.w;
    }
    float4 env = make_float4(0.f, 0.f, 0.f, 0.f);
    #pragma unroll
    for (int i = 0; i < 8; ++i) {
      const float r0 = rv[i*3], r1 = rv[i*3+1], r2 = rv[i*3+2];
      const float rr0 = r0*r0, rr1 = r1*r1, rr2 = r2*r2;
      const float rr3 = r0*r1, rr4 = r0*r2, rr5 = r1*r2;
      const float* Gp = Gl + i * 96 + 4 * ob;
      const float4 q00 = *(const float4*)(Gp);
      const float4 q11 = *(const float4*)(Gp + 16);
      const float4 q22 = *(const float4*)(Gp + 32);
      const float4 q01 = *(const float4*)(Gp + 48);
      const float4 q02 = *(const float4*)(Gp + 64);
      const float4 q12 = *(const float4*)(Gp + 80);
      const float4 io  = *(const float4*)(eion + ((size_t)sp * 8 + i) * 16 + 4 * ob);
#define ENVC(c) { float n2 = q00.c*rr0 + q11.c*rr1 + q22.c*rr2 \
                           + q01.c*rr3 + q02.c*rr4 + q12.c*rr5; \
                  n2 = fmaxf(n2, 0.f); \
                  env.c += __expf(-sqrtf(n2)) * io.c; }
      ENVC(x) ENVC(y) ENVC(z) ENVC(w)
#undef ENVC
    }
    const float* mp = Mw + n * 20 + 4 * ob;
    float4 y = *(const float4*)mp;
    const size_t pair = (size_t)bidx * 2 + sp;
    // lanes 0..63 -> offsets 0,4,...,252: fully coalesced 1KB/wave store
    *(float4*)(ws + pair * 256 + n * 16 + 4 * ob) =
        make_float4(y.x * env.x, y.y * env.y, y.z * env.z, y.w * env.w);
  }
}

// ---------------- kernel 2: cofactor via 16-lane LU ----------------
// One wave per block (64 threads); four 16-lane groups handle FOUR distinct
// pairs. A = M^T, fp32 LU with virtual partial pivoting;
// cof[i] = M[i,0]*det*x[i], x = A^{-1} e0 (= row 0 of M^{-1}).
__global__ __launch_bounds__(64)
void cof_lu(const float* __restrict__ ws,   // (8192, 256)
            float* __restrict__ out)        // (B,2,16) = (8192,16)
{
  const int lane = threadIdx.x;
  const int g  = lane >> 4;        // group -> pair within block
  const int r  = lane & 15;        // my row of A (= column r of M)
  const int gb = lane & 48;        // group base for shuffles
  const size_t pair = (size_t)blockIdx.x * 4 + g;
  const float* mg = ws + pair * 256;

  float a[16];
  #pragma unroll
  for (int c = 0; c < 16; ++c) a[c] = mg[c * 16 + r];

  float det = 1.0f;
  int sign = 0;
  unsigned retired = 0;
  unsigned pp0 = 0, pp1 = 0;       // packed pivot indices, 4 bits each
  int srr = 0;
  float accf = (r == 0) ? 1.0f : 0.0f;  // forward rhs (P e0 component)
  float acc2 = 0.0f;                    // z captured at my retirement

  #pragma unroll
  for (int k = 0; k < 16; ++k) {
    const bool act = ((retired >> r) & 1u) == 0u;
    const float av = act ? fabsf(a[k]) : 0.0f;
    unsigned pk = (__float_as_uint(av) & 0xFFFFFFF0u) | (unsigned)r;
    #pragma unroll
    for (int m = 1; m <= 8; m <<= 1) {
      unsigned o2 = __shfl_xor(pk, m);
      pk = (pk > o2) ? pk : o2;
    }
    const int p = (int)(pk & 15u);
    if (k < 8) pp0 |= (unsigned)p << (4 * k);
    else       pp1 |= (unsigned)p << (4 * (k - 8));
    float pv = __shfl(a[k], gb | p);
    if (fabsf(pv) < 1e-30f) pv = (pv < 0.0f) ? -1e-30f : 1e-30f;
    det *= pv;
    retired |= (1u << p);
    sign ^= (int)(__popc((~retired) & ((1u << p) - 1u)) & 1u);
    if (r == p) srr = k;
    const bool upd = act && (r != p);
    float m2 = 0.0f;
    if (upd) { m2 = a[k] / pv; a[k] = m2; }
    #pragma unroll
    for (int c = k + 1; c < 16; ++c) {
      float bcv = __shfl(a[c], gb | p);
      if (upd) a[c] = fmaf(-m2, bcv, a[c]);
    }
    // fused forward solve L z = P e0
    float zk = __shfl(accf, gb | p);
    if (r == p) acc2 = zk;
    if (upd) accf = fmaf(-m2, zk, accf);
  }
  if (sign) det = -det;

  // backward solve U x = z
  float myx = 0.0f;
  #pragma unroll
  for (int j = 15; j >= 0; --j) {
    float t = acc2 / a[j];                   // valid on pivot lane of step j
    const int pj = (int)(((j >= 8) ? (pp1 >> (4 * (j - 8)))
                                   : (pp0 >> (4 * j))) & 15u);
    float xj = __shfl(t, gb | pj);
    if (srr < j) acc2 = fmaf(-a[j], xj, acc2);
    if (r == j) myx = xj;
  }

  const float mi0 = mg[r * 16];              // M[r][0]
  out[pair * 16 + r] = mi0 * det * myx;      // all 64 lanes: 4 pairs x 16
}

extern "C" void kernel_launch(void* const* d_in, const int* in_sizes, int n_in,
                              void* d_out, int out_size, void* d_ws, size_t ws_size,
                              hipStream_t stream) {
  (void)in_sizes; (void)n_in; (void)out_size; (void)ws_size;
  const float* eq   = (const float*)d_in[0];
  const float* rei  = (const float*)d_in[1];
  const float* Wm   = (const float*)d_in[2];
  const float* bb   = (const float*)d_in[3];
  const float* edim = (const float*)d_in[4];
  const float* eion = (const float*)d_in[5];
  float* out = (float*)d_out;
  float* ws  = (float*)d_ws;   // needs 8192*256*4 = 8 MB
  hipLaunchKernelGGL(cof_matrix, dim3(2048), dim3(256), 0, stream,
                     eq, rei, Wm, bb, edim, eion, ws);
  hipLaunchKernelGGL(cof_lu, dim3(2048), dim3(64), 0, stream, ws, out);
}